// Round 5
// baseline (1578.854 us; speedup 1.0000x reference)
//
#include <hip/hip_runtime.h>
#include <hip/hip_bf16.h>

// Grouped conv2d as implicit GEMM per group:
//   out[b*64+co][h][w] = sum_{ci,kh,kw} W[b*64+co][ci][kh][kw] * x[b*64+ci][h+kh-1][w+kw-1]
// bf16 MFMA (16x16x32), fp32 accumulate.
//
// R5 changes vs R4 (stage/compute serialized; NT stores inflated writes 20%):
//  - multi-tile blocks: 4 w-adjacent tiles per block (grid 2048), 8 ci-phases
//    sharing ONE 26KB LDS buffer; cross-phase register pipeline:
//      issue_loads(p+1); comp(p); sync; cvt+ds_write(p+1); sync
//    cvt/zero deferred past comp so issued loads don't trigger early vmcnt.
//    Only the first of 8 stages is exposed.
//  - 3 blocks/CU -> each SIMD hosts 3 waves from 3 INDEPENDENT blocks
//    (per-block 1 wave/SIMD) -> natural stagger covers memory stalls.
//  - s_setprio(1) around MFMA clusters (blocks now role-split -> T5 applies).
//  - reverted nontemporal stores (R4: WRITE_SIZE 557->670MB regression).

typedef __bf16 bf16x8 __attribute__((ext_vector_type(8)));
typedef float  f32x4  __attribute__((ext_vector_type(4)));

#define NB 32
#define NH 256
#define NW 256
#define TILE_H 4
#define TILE_W 64
#define XROWS 6     // TILE_H + 2 (halo)
#define XCOLS 68    // TILE_W + 2, padded
#define HWSZ ((size_t)NH * NW)

template<int P> struct IC { static constexpr int v = P; };

// ---------------------------------------------------------------------------
// Repack weights into MFMA A-fragment order:
//   pk[((b*9+tap)*4+mt)*2+kc][lane][j]  (bf16, 16B per lane)
// value = W[b*64 + mt*16 + (lane&15)][kc*32 + (lane>>4)*8 + j][tap]
// ---------------------------------------------------------------------------
__global__ void repack_weights_kernel(const float* __restrict__ wsrc,
                                      __bf16* __restrict__ pk) {
    int t = blockIdx.x * blockDim.x + threadIdx.x;
    if (t >= NB * 9 * 4 * 2 * 64) return;
    int lane = t & 63;
    int r = t >> 6;
    int kc = r & 1;  r >>= 1;
    int mt = r & 3;  r >>= 2;
    int tap = r % 9;
    int b   = r / 9;
    int co  = b * 64 + mt * 16 + (lane & 15);
    int ci0 = kc * 32 + (lane >> 4) * 8;
    bf16x8 v;
#pragma unroll
    for (int j = 0; j < 8; ++j) {
        v[j] = (__bf16)wsrc[(co * 64 + ci0 + j) * 9 + tap];
    }
    *reinterpret_cast<bf16x8*>(pk + (size_t)t * 8) = v;
}

// ---------------------------------------------------------------------------
// Main conv kernel. Block = (group b, 4 output rows, 4 w-tiles of 64 cols).
// LDS holds ONE 32-ci half-tile: xs[r][c][32], octet o at 8*(o ^ ((c>>1)&3)).
// Phases p=0..7: tile=p>>1 (w0=(p>>1)*64), kc=p&1.
// ---------------------------------------------------------------------------
__launch_bounds__(256, 3)
__global__ void conv_mfma_kernel(const float* __restrict__ x,
                                 const __bf16* __restrict__ pk,
                                 float* __restrict__ out) {
    __shared__ __align__(16) __bf16 xs[XROWS * XCOLS * 32];   // 26112 B

    // XCD-aware bijective swizzle: 2048 blocks, 8 XCDs -> 256-chunk per XCD
    const int orig = blockIdx.x;
    const int wg   = (orig & 7) * 256 + (orig >> 3);
    const int b    = wg >> 6;            // 0..31
    const int by   = wg & 63;            // 0..63
    const int h0   = by * TILE_H;

    const int tid  = threadIdx.x;
    const int wid  = tid >> 6;
    const int lane = tid & 63;
    const int nl   = lane & 15;
    const int kgrp = lane >> 4;          // 0..3

    const __bf16* pkb = pk + (size_t)b * 9 * 4096;

    // A-fragment double buffer; preload (kc0, tap0) into af[0]
    bf16x8 af[2][4];
#pragma unroll
    for (int mt = 0; mt < 4; ++mt)
        af[0][mt] = *reinterpret_cast<const bf16x8*>(pkb + ((mt * 2) * 64 + lane) * 8);

    f32x4 acc[4][4];   // [mt][q]
#pragma unroll
    for (int mt = 0; mt < 4; ++mt)
#pragma unroll
        for (int q = 0; q < 4; ++q)
            acc[mt][q] = (f32x4){0.f, 0.f, 0.f, 0.f};

    // staging constants (main region: thread = column c = lane, oct = wid)
    const int c    = lane;
    const int sciw = (wid ^ ((c >> 1) & 3)) * 8;   // swizzled octet offset
    // halo constants (threads 0..47: columns 64,65)
    const int hr    = tid >> 3;              // 0..5
    const int hside = (tid >> 2) & 1;        // 0,1
    const int hoct  = tid & 3;               // local ci octet
    const int hch   = 64 + hside;

    float sv[XROWS][8];   // staged main values (issued early, cvt deferred)
    float hv[8];          // staged halo values

    // Issue the 48(+8) global loads for phase p. NO cvt/zero here — that
    // would force an early vmcnt wait; deferred to write_lds.
    auto issue_loads = [&](int p) {
        const int w0n = (p >> 1) * TILE_W;
        const int kcn = p & 1;
        const int w   = w0n - 1 + c;
        const int wcl = min(max(w, 0), NW - 1);
        const float* colp = x + (size_t)(b * 64 + kcn * 32 + wid * 8) * HWSZ + wcl;
#pragma unroll
        for (int r = 0; r < XROWS; ++r) {
            const int h  = h0 - 1 + r;
            const int hc = min(max(h, 0), NH - 1);
            const float* src = colp + (size_t)hc * NW;
#pragma unroll
            for (int j = 0; j < 8; ++j) sv[r][j] = src[j * HWSZ];
        }
        if (tid < 48) {
            const int hw  = w0n + 63 + hside;
            const int hwc = min(hw, NW - 1);
            const int h   = h0 - 1 + hr;
            const int hc  = min(max(h, 0), NH - 1);
            const float* src = x + ((size_t)(b * 64 + kcn * 32 + hoct * 8) * NH + hc) * NW + hwc;
#pragma unroll
            for (int j = 0; j < 8; ++j) hv[j] = src[j * HWSZ];
        }
    };

    // Convert + zero-predicate + LDS write for phase p (after comp(p-1)).
    auto write_lds = [&](int p) {
        const int w0n  = (p >> 1) * TILE_W;
        const int w    = w0n - 1 + c;
        const bool wbad = (w < 0) || (w > NW - 1);
#pragma unroll
        for (int r = 0; r < XROWS; ++r) {
            const int h = h0 - 1 + r;
            const bool z = wbad || (h < 0) || (h > NH - 1);
            bf16x8 o;
#pragma unroll
            for (int j = 0; j < 8; ++j) o[j] = z ? (__bf16)0.f : (__bf16)sv[r][j];
            *reinterpret_cast<bf16x8*>(xs + (r * XCOLS + c) * 32 + sciw) = o;
        }
        if (tid < 48) {
            const int hw = w0n + 63 + hside;
            const int h  = h0 - 1 + hr;
            const bool z = (hw > NW - 1) || (h < 0) || (h > NH - 1);
            bf16x8 o;
#pragma unroll
            for (int j = 0; j < 8; ++j) o[j] = z ? (__bf16)0.f : (__bf16)hv[j];
            // slot(64)=slot(65)=0 -> octet position = hoct
            *reinterpret_cast<bf16x8*>(xs + (hr * XCOLS + hch) * 32 + hoct * 8) = o;
        }
    };

    // Compute phase with parity PAR = p&1 (af parity compile-time; rule #20).
    // even: tap frag af[tap&1], prefetch -> af[(tap+1)&1]
    // odd : tap frag af[(tap+1)&1], prefetch -> af[tap&1]
    auto comp = [&](auto parc) {
        constexpr int PAR = decltype(parc)::v;
#pragma unroll
        for (int tap = 0; tap < 9; ++tap) {
            const int ntap = (tap < 8) ? tap + 1 : 0;
            const int nkc  = (tap < 8) ? PAR : (PAR ^ 1);
            const int slot = (tap + 1 + PAR) & 1;
#pragma unroll
            for (int mt = 0; mt < 4; ++mt)
                af[slot][mt] = *reinterpret_cast<const bf16x8*>(
                    pkb + ntap * 4096 + ((mt * 2 + nkc) * 64 + lane) * 8);
            const int kh = tap / 3;
            const int kw = tap - kh * 3;
            const int rowbase = (wid + kh) * XCOLS;
            const int fs = (tap + PAR) & 1;
            __builtin_amdgcn_s_setprio(1);
#pragma unroll
            for (int q = 0; q < 4; ++q) {
                const int cc = q * 16 + nl + kw;          // 0..65
                const int sl = (cc >> 1) & 3;
                bf16x8 bfv = *reinterpret_cast<const bf16x8*>(
                    xs + (rowbase + cc) * 32 + ((kgrp ^ sl) * 8));
#pragma unroll
                for (int mt = 0; mt < 4; ++mt)
                    acc[mt][q] = __builtin_amdgcn_mfma_f32_16x16x32_bf16(
                        af[fs][mt], bfv, acc[mt][q], 0, 0, 0);
            }
            __builtin_amdgcn_s_setprio(0);
        }
    };

    // Epilogue: D lane layout col=lane&15, row=(lane>>4)*4+reg. Plain stores.
    auto epilogue = [&](int w0) {
        const int h    = h0 + wid;
        const int mrow = kgrp * 4;
#pragma unroll
        for (int mt = 0; mt < 4; ++mt) {
#pragma unroll
            for (int q = 0; q < 4; ++q) {
                const int ww = w0 + q * 16 + nl;
#pragma unroll
                for (int rg = 0; rg < 4; ++rg) {
                    const int co = mt * 16 + mrow + rg;
                    out[((size_t)(b * 64 + co) * NH + h) * NW + ww] = acc[mt][q][rg];
                }
            }
        }
    };

    // ---- prologue: stage phase 0 (the only fully exposed stage) ----
    issue_loads(0);
    write_lds(0);
    __syncthreads();

#pragma unroll 1
    for (int tt = 0; tt < 4; ++tt) {
        // even phase p = 2tt (kc=0)
        issue_loads(2 * tt + 1);
        comp(IC<0>{});
        __syncthreads();
        write_lds(2 * tt + 1);
        __syncthreads();

        // odd phase p = 2tt+1 (kc=1)
        if (tt < 3) issue_loads(2 * tt + 2);
        comp(IC<1>{});
        epilogue(tt * TILE_W);
#pragma unroll
        for (int mt = 0; mt < 4; ++mt)
#pragma unroll
            for (int q = 0; q < 4; ++q)
                acc[mt][q] = (f32x4){0.f, 0.f, 0.f, 0.f};
        if (tt < 3) {
            __syncthreads();
            write_lds(2 * tt + 2);
            __syncthreads();
        }
    }
}

extern "C" void kernel_launch(void* const* d_in, const int* in_sizes, int n_in,
                              void* d_out, int out_size, void* d_ws, size_t ws_size,
                              hipStream_t stream) {
    const float* x = (const float*)d_in[0];     // [1, 32*64, 256, 256] fp32
    const float* w = (const float*)d_in[1];     // [2048, 64, 3, 3] fp32
    float* out = (float*)d_out;                 // [1, 2048, 256, 256] fp32
    __bf16* pk = (__bf16*)d_ws;                 // 2.25 MB repacked bf16 weights

    {
        int total = NB * 9 * 4 * 2 * 64;        // 147456
        int blk = 256;
        int grid = (total + blk - 1) / blk;     // 576
        hipLaunchKernelGGL(repack_weights_kernel, dim3(grid), dim3(blk), 0, stream,
                           w, pk);
    }
    {
        dim3 grid(2048);                        // 1D, swizzled in-kernel; 4 tiles/block
        hipLaunchKernelGGL(conv_mfma_kernel, grid, dim3(256), 0, stream,
                           x, pk, out);
    }
}

// Round 6
// 1325.609 us; speedup vs baseline: 1.1910x; 1.1910x over previous
//
#include <hip/hip_runtime.h>
#include <hip/hip_bf16.h>

// Grouped conv2d as implicit GEMM per group:
//   out[b*64+co][h][w] = sum_{ci,kh,kw} W[b*64+co][ci][kh][kw] * x[b*64+ci][h+kh-1][w+kw-1]
// bf16 MFMA (16x16x32), fp32 accumulate.
//
// R6 changes vs R5 (register pipeline spilled: FETCH 2.3GB, scratch traffic):
//  - producer/consumer wave specialization: 512-thread blocks, waves 0-3
//    compute (R4's verified per-wave work), waves 4-7 stage (R4's verified
//    256-thread staging, 16 live floats ping-pong -> no spill).
//  - two 26KB LDS buffers, ONE barrier per phase:
//      [prod: stage(p+1)->buf[(p+1)&1] | cons: comp(p) from buf[p&1]]; sync
//    Staging latency hides under consumer MFMA on the same SIMD.
//  - __launch_bounds__(512,4): 128-VGPR cap -> 2 blocks/CU (16 waves/CU),
//    per SIMD 2 producer + 2 consumer waves from independent blocks.
//  - af prefetch chain: pk depends only on (b,tap,kc), parity alternates
//    even/odd phase -> carries across all 8 phases.

typedef __bf16 bf16x8 __attribute__((ext_vector_type(8)));
typedef float  f32x4  __attribute__((ext_vector_type(4)));

#define NB 32
#define NH 256
#define NW 256
#define TILE_H 4
#define TILE_W 64
#define XROWS 6     // TILE_H + 2 (halo)
#define XCOLS 68    // TILE_W + 2, padded
#define XS32 (XROWS * XCOLS * 32)   // 13056 bf16 = 26112 B per buffer
#define HWSZ ((size_t)NH * NW)

template<int P> struct IC { static constexpr int v = P; };

// ---------------------------------------------------------------------------
// Repack weights into MFMA A-fragment order:
//   pk[((b*9+tap)*4+mt)*2+kc][lane][j]  (bf16, 16B per lane)
// value = W[b*64 + mt*16 + (lane&15)][kc*32 + (lane>>4)*8 + j][tap]
// ---------------------------------------------------------------------------
__global__ void repack_weights_kernel(const float* __restrict__ wsrc,
                                      __bf16* __restrict__ pk) {
    int t = blockIdx.x * blockDim.x + threadIdx.x;
    if (t >= NB * 9 * 4 * 2 * 64) return;
    int lane = t & 63;
    int r = t >> 6;
    int kc = r & 1;  r >>= 1;
    int mt = r & 3;  r >>= 2;
    int tap = r % 9;
    int b   = r / 9;
    int co  = b * 64 + mt * 16 + (lane & 15);
    int ci0 = kc * 32 + (lane >> 4) * 8;
    bf16x8 v;
#pragma unroll
    for (int j = 0; j < 8; ++j) {
        v[j] = (__bf16)wsrc[(co * 64 + ci0 + j) * 9 + tap];
    }
    *reinterpret_cast<bf16x8*>(pk + (size_t)t * 8) = v;
}

// ---------------------------------------------------------------------------
// Main conv kernel. Block = (group b, 4 output rows, 4 w-tiles), 8 waves:
// waves 0-3 consume (MFMA), waves 4-7 produce (stage X into LDS).
// LDS: xs[2][6][68][32] bf16; octet o of column c at 8*(o ^ ((c>>1)&3)).
// Phases p=0..7: tile=p>>1 (w0=(p>>1)*64), kc=p&1, buffer=p&1.
// ---------------------------------------------------------------------------
__launch_bounds__(512, 4)
__global__ void conv_mfma_kernel(const float* __restrict__ x,
                                 const __bf16* __restrict__ pk,
                                 float* __restrict__ out) {
    __shared__ __align__(16) __bf16 xs[2][XS32];

    // XCD-aware bijective swizzle: 2048 blocks, 8 XCDs -> 256-chunk per XCD
    const int orig = blockIdx.x;
    const int wg   = (orig & 7) * 256 + (orig >> 3);
    const int b    = wg >> 6;            // 0..31
    const int by   = wg & 63;            // 0..63
    const int h0   = by * TILE_H;

    const int tid  = threadIdx.x;
    const int wid  = tid >> 6;           // 0..7
    const int lane = tid & 63;
    const int nl   = lane & 15;
    const int kgrp = lane >> 4;          // 0..3
    const bool is_prod = (wid >= 4);

    const __bf16* pkb = pk + (size_t)b * 9 * 4096;

    // ---------------- producer state ----------------
    const int ptid = tid - 256;          // 0..255 for producers
    const int pwid = wid - 4;            // ci-octet index 0..3
    const int c    = lane;               // column 0..63 -> w = w0-1+c
    const int sciw = (pwid ^ ((c >> 1) & 3)) * 8;
    // halo: producer threads 0..47 handle columns 64,65
    const int hr    = ptid >> 3;             // 0..5
    const int hside = (ptid >> 2) & 1;       // 0,1
    const int hoct  = ptid & 3;              // local ci octet
    const int hch   = 64 + hside;

    // Stage phase p into buf (producer waves only; 16 live floats ping-pong).
    auto stage = [&](int p, __bf16* buf) {
        const int w0n = (p >> 1) * TILE_W;
        const int kcn = p & 1;
        const int w   = w0n - 1 + c;
        const int wcl = min(max(w, 0), NW - 1);
        const bool wbad = (w != wcl);
        const float* colp = x + (size_t)(b * 64 + kcn * 32 + pwid * 8) * HWSZ + wcl;

        // halo loads first (longest exposure), store at end
        float hv[8];
        bool hz = false;
        if (ptid < 48) {
            const int hw  = w0n + 63 + hside;
            const int hwc = min(hw, NW - 1);
            const int h   = h0 - 1 + hr;
            const int hc  = min(max(h, 0), NH - 1);
            hz = (h != hc) || (hw != hwc);
            const float* src = x + ((size_t)(b * 64 + kcn * 32 + hoct * 8) * NH + hc) * NW + hwc;
#pragma unroll
            for (int j = 0; j < 8; ++j) hv[j] = src[j * HWSZ];
        }

        float va[8], vb[8];
        auto load8 = [&](int r, float* v) {
            const int h  = h0 - 1 + r;
            const int hc = min(max(h, 0), NH - 1);
            const float* src = colp + (size_t)hc * NW;
#pragma unroll
            for (int j = 0; j < 8; ++j) v[j] = src[j * HWSZ];
            if (wbad || h != hc) {
#pragma unroll
                for (int j = 0; j < 8; ++j) v[j] = 0.f;
            }
        };
        auto store8 = [&](int r, const float* v) {
            bf16x8 o;
#pragma unroll
            for (int j = 0; j < 8; ++j) o[j] = (__bf16)v[j];
            *reinterpret_cast<bf16x8*>(buf + (r * XCOLS + c) * 32 + sciw) = o;
        };

        load8(0, va);
        load8(1, vb);
        store8(0, va); load8(2, va);
        store8(1, vb); load8(3, vb);
        store8(2, va); load8(4, va);
        store8(3, vb); load8(5, vb);
        store8(4, va);
        store8(5, vb);

        if (ptid < 48) {
            bf16x8 o;
#pragma unroll
            for (int j = 0; j < 8; ++j) o[j] = hz ? (__bf16)0.f : (__bf16)hv[j];
            // slot(64)=slot(65)=0 -> octet position = hoct
            *reinterpret_cast<bf16x8*>(buf + (hr * XCOLS + hch) * 32 + hoct * 8) = o;
        }
    };

    // ---------------- consumer state ----------------
    bf16x8 af[2][4];
    f32x4 acc[4][4];   // [mt][q]
    if (!is_prod) {
#pragma unroll
        for (int mt = 0; mt < 4; ++mt)   // preload (tap0, kc0) -> af[0]
            af[0][mt] = *reinterpret_cast<const bf16x8*>(pkb + ((mt * 2) * 64 + lane) * 8);
#pragma unroll
        for (int mt = 0; mt < 4; ++mt)
#pragma unroll
            for (int q = 0; q < 4; ++q)
                acc[mt][q] = (f32x4){0.f, 0.f, 0.f, 0.f};
    }

    // Compute one phase; PAR = p&1 compile-time (af parity; rule #20).
    auto comp = [&](auto parc, const __bf16* buf) {
        constexpr int PAR = decltype(parc)::v;
#pragma unroll
        for (int tap = 0; tap < 9; ++tap) {
            const int ntap = (tap < 8) ? tap + 1 : 0;
            const int nkc  = (tap < 8) ? PAR : (PAR ^ 1);
            const int slot = (tap + 1 + PAR) & 1;
#pragma unroll
            for (int mt = 0; mt < 4; ++mt)
                af[slot][mt] = *reinterpret_cast<const bf16x8*>(
                    pkb + ntap * 4096 + ((mt * 2 + nkc) * 64 + lane) * 8);
            const int kh = tap / 3;
            const int kw = tap - kh * 3;
            const int rowbase = (wid + kh) * XCOLS;
            const int fs = (tap + PAR) & 1;
            __builtin_amdgcn_s_setprio(1);
#pragma unroll
            for (int q = 0; q < 4; ++q) {
                const int cc = q * 16 + nl + kw;          // 0..65
                const int sl = (cc >> 1) & 3;
                bf16x8 bfv = *reinterpret_cast<const bf16x8*>(
                    buf + (rowbase + cc) * 32 + ((kgrp ^ sl) * 8));
#pragma unroll
                for (int mt = 0; mt < 4; ++mt)
                    acc[mt][q] = __builtin_amdgcn_mfma_f32_16x16x32_bf16(
                        af[fs][mt], bfv, acc[mt][q], 0, 0, 0);
            }
            __builtin_amdgcn_s_setprio(0);
        }
    };

    // Epilogue: D lane layout col=lane&15, row=(lane>>4)*4+reg.
    auto epilogue = [&](int w0) {
        const int h    = h0 + wid;       // consumer wid 0..3
        const int mrow = kgrp * 4;
#pragma unroll
        for (int mt = 0; mt < 4; ++mt) {
#pragma unroll
            for (int q = 0; q < 4; ++q) {
                const int ww = w0 + q * 16 + nl;
#pragma unroll
                for (int rg = 0; rg < 4; ++rg) {
                    const int co = mt * 16 + mrow + rg;
                    out[((size_t)(b * 64 + co) * NH + h) * NW + ww] = acc[mt][q][rg];
                }
            }
        }
    };

    // ---- prologue: producers stage phase 0 (only exposed stage) ----
    if (is_prod) stage(0, xs[0]);
    __syncthreads();

#pragma unroll 1
    for (int tt = 0; tt < 4; ++tt) {
        // phase p = 2tt (even, kc=0, buf0); producers fill buf1 for p+1
        if (is_prod) {
            stage(2 * tt + 1, xs[1]);
        } else {
            comp(IC<0>{}, xs[0]);
        }
        __syncthreads();

        // phase p = 2tt+1 (odd, kc=1, buf1); producers fill buf0 for p+2
        if (is_prod) {
            if (tt < 3) stage(2 * tt + 2, xs[0]);
        } else {
            comp(IC<1>{}, xs[1]);
            epilogue(tt * TILE_W);
#pragma unroll
            for (int mt = 0; mt < 4; ++mt)
#pragma unroll
                for (int q = 0; q < 4; ++q)
                    acc[mt][q] = (f32x4){0.f, 0.f, 0.f, 0.f};
        }
        __syncthreads();
    }
}

extern "C" void kernel_launch(void* const* d_in, const int* in_sizes, int n_in,
                              void* d_out, int out_size, void* d_ws, size_t ws_size,
                              hipStream_t stream) {
    const float* x = (const float*)d_in[0];     // [1, 32*64, 256, 256] fp32
    const float* w = (const float*)d_in[1];     // [2048, 64, 3, 3] fp32
    float* out = (float*)d_out;                 // [1, 2048, 256, 256] fp32
    __bf16* pk = (__bf16*)d_ws;                 // 2.25 MB repacked bf16 weights

    {
        int total = NB * 9 * 4 * 2 * 64;        // 147456
        int blk = 256;
        int grid = (total + blk - 1) / blk;     // 576
        hipLaunchKernelGGL(repack_weights_kernel, dim3(grid), dim3(blk), 0, stream,
                           w, pk);
    }
    {
        dim3 grid(2048);                        // 1D, swizzled in-kernel; 4 tiles/block
        hipLaunchKernelGGL(conv_mfma_kernel, grid, dim3(512), 0, stream,
                           x, pk, out);
    }
}

// Round 7
// 311.603 us; speedup vs baseline: 5.0669x; 4.2542x over previous
//
#include <hip/hip_runtime.h>
#include <hip/hip_bf16.h>

// Grouped conv2d as implicit GEMM per group:
//   out[b*64+co][h][w] = sum_{ci,kh,kw} W[b*64+co][ci][kh][kw] * x[b*64+ci][h+kh-1][w+kw-1]
// bf16 MFMA (16x16x32), fp32 accumulate.
//
// R7 = R4 (best verified: 370us, 112 VGPR, 0 conflicts, no spill) + ONE change:
//  - A-fragment prefetch deepened from depth-1 to depth-2 via a 4-slot ring
//    indexed by compile-time g = kc*9+tap. Theory: per-tap MFMA (~78cy) with
//    depth-1 af prefetch leaves ~150-300cy of L2 latency exposed per tap
//    (dominant serial term; occupancy/conflict fixes at R3/R4 moved nothing).
//    Depth-2 covers ~2 taps (~300-500cy wall) >= L2 latency.
//  - prologue issues g=0,1 BEFORE staging (lands under stage latency).
//  R5/R6 lesson: acc(64)+af leaves ~20 VGPR headroom; this adds only 16
//  (3 live ring slots vs 2) -> peak ~156 < 170 (3 waves/SIMD). No divergent
//  cross-barrier liveness.

typedef __bf16 bf16x8 __attribute__((ext_vector_type(8)));
typedef float  f32x4  __attribute__((ext_vector_type(4)));

#define NB 32
#define NH 256
#define NW 256
#define TILE_H 4
#define TILE_W 64
#define XROWS 6     // TILE_H + 2 (halo)
#define XCOLS 68    // TILE_W + 2, padded

// ---------------------------------------------------------------------------
// Repack weights into MFMA A-fragment order:
//   pk[((b*9+tap)*4+mt)*2+kc][lane][j]  (bf16, 16B per lane)
// value = W[b*64 + mt*16 + (lane&15)][kc*32 + (lane>>4)*8 + j][tap]
// ---------------------------------------------------------------------------
__global__ void repack_weights_kernel(const float* __restrict__ wsrc,
                                      __bf16* __restrict__ pk) {
    int t = blockIdx.x * blockDim.x + threadIdx.x;
    if (t >= NB * 9 * 4 * 2 * 64) return;
    int lane = t & 63;
    int r = t >> 6;
    int kc = r & 1;  r >>= 1;
    int mt = r & 3;  r >>= 2;
    int tap = r % 9;
    int b   = r / 9;
    int co  = b * 64 + mt * 16 + (lane & 15);
    int ci0 = kc * 32 + (lane >> 4) * 8;
    bf16x8 v;
#pragma unroll
    for (int j = 0; j < 8; ++j) {
        v[j] = (__bf16)wsrc[(co * 64 + ci0 + j) * 9 + tap];
    }
    *reinterpret_cast<bf16x8*>(pk + (size_t)t * 8) = v;
}

// ---------------------------------------------------------------------------
// Main conv kernel. Block = (group b, 4 output rows, 64 output cols), 4 waves.
// LDS holds ONE 32-ci half-tile: xs[r][c][32], octet of local ci o stored at
// 8*(o ^ ((c>>1)&3)). Two phases kc=0,1 reuse the buffer.
// ---------------------------------------------------------------------------
__launch_bounds__(256)
__global__ void conv_mfma_kernel(const float* __restrict__ x,
                                 const __bf16* __restrict__ pk,
                                 float* __restrict__ out) {
    __shared__ __align__(16) __bf16 xs[XROWS * XCOLS * 32];   // 26112 B

    // XCD-aware bijective swizzle: 8192 blocks, 8 XCDs
    const int orig = blockIdx.x;
    const int wg   = (orig & 7) * 1024 + (orig >> 3);
    const int b    = wg >> 8;            // 0..31
    const int by   = (wg >> 2) & 63;     // 0..63
    const int bx   = wg & 3;             // 0..3
    const int h0   = by * TILE_H;
    const int w0   = bx * TILE_W;

    const int tid  = threadIdx.x;
    const int wid  = tid >> 6;
    const int lane = tid & 63;
    const int nl   = lane & 15;
    const int kgrp = lane >> 4;          // 0..3

    const __bf16* pkb = pk + (size_t)b * 9 * 4096;

    // A-fragment 4-slot ring over g = kc*9+tap (all indices compile-time).
    bf16x8 af[4][4];
    auto load_af = [&](int g) {           // g in [0,18)
        const int tap = (g >= 9) ? g - 9 : g;
        const int kc  = (g >= 9) ? 1 : 0;
        const int sl  = g & 3;
#pragma unroll
        for (int mt = 0; mt < 4; ++mt)
            af[sl][mt] = *reinterpret_cast<const bf16x8*>(
                pkb + tap * 4096 + ((mt * 2 + kc) * 64 + lane) * 8);
    };

    // prologue: issue g=0,1 now; they land under the staging latency
    load_af(0);
    load_af(1);

    f32x4 acc[4][4];   // [mt][q]
#pragma unroll
    for (int mt = 0; mt < 4; ++mt)
#pragma unroll
        for (int q = 0; q < 4; ++q)
            acc[mt][q] = (f32x4){0.f, 0.f, 0.f, 0.f};

    // staging thread constants (main region: thread = column c = lane, oct = wid)
    const int c    = lane;               // 0..63 -> w = w0-1+c
    const int w    = w0 - 1 + c;
    const int wcl  = min(max(w, 0), NW - 1);
    const bool wbad = (w != wcl);
    const int sciw = ((wid ^ ((c >> 1) & 3)) * 8);   // swizzled octet offset

    // halo thread constants (threads 0..47: c=64,65)
    const int hidx  = tid;
    const int hr    = hidx >> 3;             // 0..5
    const int hside = (hidx >> 2) & 1;       // 0,1 -> c = 64,65
    const int hoct  = hidx & 3;              // local ci octet
    const int hch   = 64 + hside;
    const int hw    = w0 + 63 + hside;
    const int hwc   = min(hw, NW - 1);

#pragma unroll
    for (int kc = 0; kc < 2; ++kc) {
        // ---- stage phase kc: 32 ci, coalesced scalar loads, b128 swizzled writes ----
        {
            const int cibase = b * 64 + kc * 32 + wid * 8;
            const float* colp = x + (size_t)cibase * NH * NW + wcl;

            // halo loads first (threads 0..47), store at end
            float hv[8];
            if (tid < 48) {
                const int h  = h0 - 1 + hr;
                const int hc = min(max(h, 0), NH - 1);
                const float* src = x + ((size_t)(b * 64 + kc * 32 + hoct * 8) * NH + hc) * NW + hwc;
#pragma unroll
                for (int j = 0; j < 8; ++j) hv[j] = src[(size_t)j * NH * NW];
                if (h != hc || hw != hwc) {
#pragma unroll
                    for (int j = 0; j < 8; ++j) hv[j] = 0.f;
                }
            }

            float va[8], vb[8];
            auto load8 = [&](int r, float* v) {
                const int h  = h0 - 1 + r;
                const int hc = min(max(h, 0), NH - 1);
                const float* src = colp + (size_t)hc * NW;
#pragma unroll
                for (int j = 0; j < 8; ++j) v[j] = src[(size_t)j * NH * NW];
                if (wbad || h != hc) {
#pragma unroll
                    for (int j = 0; j < 8; ++j) v[j] = 0.f;
                }
            };
            auto store8 = [&](int r, const float* v) {
                bf16x8 o;
#pragma unroll
                for (int j = 0; j < 8; ++j) o[j] = (__bf16)v[j];
                *reinterpret_cast<bf16x8*>(xs + (r * XCOLS + c) * 32 + sciw) = o;
            };

            load8(0, va);
            load8(1, vb);
            store8(0, va); load8(2, va);
            store8(1, vb); load8(3, vb);
            store8(2, va); load8(4, va);
            store8(3, vb); load8(5, vb);
            store8(4, va);
            store8(5, vb);

            if (tid < 48) {
                bf16x8 o;
#pragma unroll
                for (int j = 0; j < 8; ++j) o[j] = (__bf16)hv[j];
                // slot(64)=slot(65)=0 -> octet position = hoct
                *reinterpret_cast<bf16x8*>(xs + (hr * XCOLS + hch) * 32 + hoct * 8) = o;
            }
        }
        __syncthreads();

        // ---- compute phase kc: 9 taps, K=32 slice per tap; af ring depth-2 ----
#pragma unroll
        for (int tap = 0; tap < 9; ++tap) {
            const int g = kc * 9 + tap;
            if (g + 2 < 18) load_af(g + 2);    // depth-2 prefetch
            const int kh = tap / 3;
            const int kw = tap - kh * 3;
            const int rowbase = (wid + kh) * XCOLS;
            const int fs = g & 3;
#pragma unroll
            for (int q = 0; q < 4; ++q) {
                const int cc   = q * 16 + nl + kw;          // 0..65
                const int slot = (cc >> 1) & 3;
                bf16x8 bfv = *reinterpret_cast<const bf16x8*>(
                    xs + (rowbase + cc) * 32 + ((kgrp ^ slot) * 8));
#pragma unroll
                for (int mt = 0; mt < 4; ++mt)
                    acc[mt][q] = __builtin_amdgcn_mfma_f32_16x16x32_bf16(
                        af[fs][mt], bfv, acc[mt][q], 0, 0, 0);
            }
        }
        if (kc == 0) __syncthreads();   // protect xs before phase-1 overwrite
    }

    // ---- epilogue: D lane layout col=lane&15, row=(lane>>4)*4+reg ----
    const int mrow = kgrp * 4;
    const int h = h0 + wid;
#pragma unroll
    for (int mt = 0; mt < 4; ++mt) {
#pragma unroll
        for (int q = 0; q < 4; ++q) {
            const int ww = w0 + q * 16 + nl;
#pragma unroll
            for (int rg = 0; rg < 4; ++rg) {
                const int co = mt * 16 + mrow + rg;
                out[((size_t)(b * 64 + co) * NH + h) * NW + ww] = acc[mt][q][rg];
            }
        }
    }
}

extern "C" void kernel_launch(void* const* d_in, const int* in_sizes, int n_in,
                              void* d_out, int out_size, void* d_ws, size_t ws_size,
                              hipStream_t stream) {
    const float* x = (const float*)d_in[0];     // [1, 32*64, 256, 256] fp32
    const float* w = (const float*)d_in[1];     // [2048, 64, 3, 3] fp32
    float* out = (float*)d_out;                 // [1, 2048, 256, 256] fp32
    __bf16* pk = (__bf16*)d_ws;                 // 2.25 MB repacked bf16 weights

    {
        int total = NB * 9 * 4 * 2 * 64;        // 147456
        int blk = 256;
        int grid = (total + blk - 1) / blk;     // 576
        hipLaunchKernelGGL(repack_weights_kernel, dim3(grid), dim3(blk), 0, stream,
                           w, pk);
    }
    {
        dim3 grid(8192);                        // 1D, swizzled in-kernel
        hipLaunchKernelGGL(conv_mfma_kernel, grid, dim3(256), 0, stream,
                           x, pk, out);
    }
}